// Round 17
// baseline (659.500 us; speedup 1.0000x reference)
//
#include <hip/hip_runtime.h>
#include <hip/hip_fp16.h>
#include <cstddef>
#include <cstdint>

// ---------------------------------------------------------------------------
// SimpleHAN on MI355X — round 16:
//   - mfma_gemm: BK 32 -> 64 (LDS 64KB, still 2 blocks/CU at 512 thr).
//     Halves the vmcnt(0)+barrier drains (K=128: 4->2 iters) and doubles
//     loads in flight per stage. Occupancy unchanged (~50%).
//   - att kernels merged pairwise via blockIdx.y (4 -> 2 dispatches).
//   - everything else unchanged from round 15 (645us).
// ---------------------------------------------------------------------------

#define HID        256
#define HEADS      8
#define NEG_SLOPE  0.2f
#define ECAP       48

#define BSH     7
#define BNODES  128
#define MAXNB   512
#define CH      2048

typedef __attribute__((ext_vector_type(8))) short short8v;
typedef __attribute__((ext_vector_type(4))) float float4v;

static __device__ __forceinline__ unsigned short f32_to_bf16(float v) {
    union { float f; unsigned u; } c; c.f = v;
    unsigned r = c.u + 0x7FFFu + ((c.u >> 16) & 1u);
    return (unsigned short)(r >> 16);
}
static __device__ __forceinline__ float bf16_to_f32(unsigned short b) {
    union { unsigned u; float f; } c; c.u = ((unsigned)b) << 16;
    return c.f;
}
static __device__ __forceinline__ void split_bf16(float v, unsigned short& hi, unsigned short& lo) {
    hi = f32_to_bf16(v);
    lo = f32_to_bf16(v - bf16_to_f32(hi));
}
static __device__ __forceinline__ void gload_lds16(const void* g, void* l) {
    __builtin_amdgcn_global_load_lds((const __attribute__((address_space(1))) void*)g,
                                     (__attribute__((address_space(3))) void*)l, 16, 0, 0);
}

// ------------------------- MFMA GEMM (bf16x3 split) ------------------------
// C[M,N] = (Ahi+Alo)[M,K] @ (Bthi+Btlo)[N,K]^T  (+bias)
// 512 threads = 8 waves (2 row-halves x 4 col-quarters); per-wave 64x32.
// BK=64: per iter each wave issues 8 global_load_lds then ONE drain.
// MODE 1: fp16 out (col<256 -> Cf16a else Cf16b) + bias; blockIdx.z==1
//         switches to operand set 2 and Cf16c.  MODE 2: fp32+bias+relu.
// MODE 3: transposed split bf16 out (weight-fold GEMM).
template<int MODE>
__global__ __launch_bounds__(512) void mfma_gemm_kernel(
    const unsigned short* __restrict__ Ahi, const unsigned short* __restrict__ Alo,
    const unsigned short* __restrict__ Bthi, const unsigned short* __restrict__ Btlo,
    const unsigned short* __restrict__ A2hi, const unsigned short* __restrict__ A2lo,
    const unsigned short* __restrict__ B2thi, const unsigned short* __restrict__ B2tlo,
    const float* __restrict__ bias,
    unsigned short* __restrict__ Chi, unsigned short* __restrict__ Clo,
    __half* __restrict__ Cf16a, __half* __restrict__ Cf16b, __half* __restrict__ Cf16c,
    float* __restrict__ Cf32,
    int M, int N, int K)
{
    __shared__ __align__(16) short lds[4 * 8192];  // 64 KB (BK=64)

    const int tid  = threadIdx.x;
    const int lane = tid & 63;
    const int w    = tid >> 6;        // 0..7
    const int wr   = w >> 2;          // row half (0..1)
    const int wc   = w & 3;           // col quarter (0..3)

    const bool z1 = (blockIdx.z == 1);
    const unsigned short* eAhi  = z1 ? A2hi  : Ahi;
    const unsigned short* eAlo  = z1 ? A2lo  : Alo;
    const unsigned short* eBthi = z1 ? B2thi : Bthi;
    const unsigned short* eBtlo = z1 ? B2tlo : Btlo;
    __half* eCf16a = z1 ? Cf16c : Cf16a;

    // XCD-chunked bijective swizzle (m204)
    const int gx   = gridDim.x;
    const int nwg  = gx * gridDim.y;
    const int flat = blockIdx.y * gx + blockIdx.x;
    const int q    = nwg >> 3, r8 = nwg & 7;
    const int xcd  = flat & 7, idx = flat >> 3;
    const int swz  = (xcd < r8) ? xcd * (q + 1) + idx
                                : r8 * (q + 1) + (xcd - r8) * q + idx;
    const int m0   = (swz / gx) * 128;
    const int n0   = (swz % gx) * 128;

    // staging role: wave pair (w>>1) per array; w&1 selects the 64-row half
    const int sarr  = w >> 1;         // 0..3: Ahi, Alo, Bthi, Btlo
    const int shalf = w & 1;
    const unsigned short* sbase = (sarr == 0) ? eAhi : (sarr == 1) ? eAlo
                                : (sarr == 2) ? eBthi : eBtlo;
    const int rowbase = (sarr < 2) ? m0 : n0;
    const int rowlim  = ((sarr < 2) ? M : N) - 1;

    float4v acc[4][2];
    #pragma unroll
    for (int i = 0; i < 4; ++i)
        #pragma unroll
        for (int j = 0; j < 2; ++j)
            acc[i][j] = (float4v){0.f, 0.f, 0.f, 0.f};

    const int kcl = lane >> 4;
    const int rl  = lane & 15;

    for (int k0 = 0; k0 < K; k0 += 64) {
        {
            int row = rowbase + shalf * 64 + lane;
            row = row > rowlim ? rowlim : row;
            const unsigned short* src = sbase + (size_t)row * K + k0;
            #pragma unroll
            for (int kc = 0; kc < 8; ++kc) {
                short* dst = &lds[sarr * 8192 + kc * 1024 + shalf * 512];
                gload_lds16(src + kc * 8, dst);
            }
        }
        __syncthreads();

        #pragma unroll
        for (int kk = 0; kk < 2; ++kk) {
            const int kb = (kk * 4 + kcl) * 1024;
            short8v ahi[4], alo[4], bhi[2], blo[2];
            #pragma unroll
            for (int i = 0; i < 4; ++i) {
                int am = wr * 64 + i * 16 + rl;
                ahi[i] = *(const short8v*)&lds[0 * 8192 + kb + am * 8];
                alo[i] = *(const short8v*)&lds[1 * 8192 + kb + am * 8];
            }
            #pragma unroll
            for (int j = 0; j < 2; ++j) {
                int bn = wc * 32 + j * 16 + rl;
                bhi[j] = *(const short8v*)&lds[2 * 8192 + kb + bn * 8];
                blo[j] = *(const short8v*)&lds[3 * 8192 + kb + bn * 8];
            }
            #pragma unroll
            for (int i = 0; i < 4; ++i)
                #pragma unroll
                for (int j = 0; j < 2; ++j) {
                    acc[i][j] = __builtin_amdgcn_mfma_f32_16x16x32_bf16(ahi[i], bhi[j], acc[i][j], 0, 0, 0);
                    acc[i][j] = __builtin_amdgcn_mfma_f32_16x16x32_bf16(ahi[i], blo[j], acc[i][j], 0, 0, 0);
                    acc[i][j] = __builtin_amdgcn_mfma_f32_16x16x32_bf16(alo[i], bhi[j], acc[i][j], 0, 0, 0);
                }
        }
        __syncthreads();
    }

    // ---- epilogue (C/D map: col=lane&15, row=(lane>>4)*4+r) ----
    const int cr = kcl * 4;
    #pragma unroll
    for (int i = 0; i < 4; ++i) {
        #pragma unroll
        for (int r = 0; r < 4; ++r) {
            int row = m0 + wr * 64 + i * 16 + cr + r;
            if (row >= M) continue;
            #pragma unroll
            for (int j = 0; j < 2; ++j) {
                int col = n0 + wc * 32 + j * 16 + rl;
                float v = acc[i][j][r];
                if (bias) v += bias[col];
                if (MODE == 1) {
                    if (col < 256) eCf16a[(size_t)row * 256 + col] = __float2half(v);
                    else           Cf16b[(size_t)row * 256 + (col - 256)] = __float2half(v);
                } else if (MODE == 2) {
                    Cf32[(size_t)row * N + col] = fmaxf(v, 0.f);
                } else {  // MODE 3: transposed split
                    unsigned short h, l;
                    split_bf16(v, h, l);
                    Chi[(size_t)col * M + row] = h;
                    Clo[(size_t)col * M + row] = l;
                }
            }
        }
    }
}

// ----------------------- unified prep (weights + x) ------------------------
__global__ void prep_kernel(
    const float* __restrict__ proj_W, const float* __restrict__ tut_W,
    const float* __restrict__ tdt_W, const float* __restrict__ cls_W1,
    unsigned short* __restrict__ pAhi,  unsigned short* __restrict__ pAlo,
    unsigned short* __restrict__ w1hi,  unsigned short* __restrict__ w1lo,
    unsigned short* __restrict__ t2Whi, unsigned short* __restrict__ t2Wlo,
    unsigned short* __restrict__ d2Whi, unsigned short* __restrict__ d2Wlo,
    unsigned short* __restrict__ cWthi, unsigned short* __restrict__ cWtlo,
    const float* __restrict__ x,
    unsigned short* __restrict__ xhi, unsigned short* __restrict__ xlo, int count4x)
{
    const int tid = blockIdx.x * blockDim.x + threadIdx.x;
    const int stride = gridDim.x * blockDim.x;
    for (int idx = tid; idx < 327680; idx += stride) {
        unsigned short h, l;
        if (idx < 32768) {
            split_bf16(proj_W[idx], h, l);
            pAhi[idx] = h; pAlo[idx] = l;
        } else if (idx < 163840) {
            int r = idx - 32768;
            int ly = r >> 16, rr = r & 65535;
            int k = rr >> 8, n = rr & 255;
            split_bf16(tut_W[r], h, l);
            if (ly == 0) { w1hi[n * 256 + k] = h;  w1lo[n * 256 + k] = l; }
            else         { t2Whi[n * 256 + k] = h; t2Wlo[n * 256 + k] = l; }
        } else if (idx < 294912) {
            int r = idx - 163840;
            int ly = r >> 16, rr = r & 65535;
            int k = rr >> 8, n = rr & 255;
            split_bf16(tdt_W[r], h, l);
            if (ly == 0) { w1hi[(256 + n) * 256 + k] = h; w1lo[(256 + n) * 256 + k] = l; }
            else         { d2Whi[n * 256 + k] = h;        d2Wlo[n * 256 + k] = l; }
        } else {
            int r = idx - 294912;
            int k = r >> 7, n = r & 127;
            split_bf16(cls_W1[r], h, l);
            cWthi[n * 256 + k] = h; cWtlo[n * 256 + k] = l;
        }
    }
    for (int i = tid; i < count4x; i += stride) {
        float4 v = reinterpret_cast<const float4*>(x)[i];
        ushort4 hh, ll;
        split_bf16(v.x, hh.x, ll.x);
        split_bf16(v.y, hh.y, ll.y);
        split_bf16(v.z, hh.z, ll.z);
        split_bf16(v.w, hh.w, ll.w);
        reinterpret_cast<ushort4*>(xhi)[i] = hh;
        reinterpret_cast<ushort4*>(xlo)[i] = ll;
    }
}

// bias1[n] = sum_k proj_b[k] * W1cat[k, n]   (fp32 exact)
__global__ void bias1_kernel(const float* __restrict__ pb,
                             const float* __restrict__ tutW,
                             const float* __restrict__ tdtW,
                             float* __restrict__ bias1)
{
    int n = blockIdx.x * blockDim.x + threadIdx.x;
    if (n >= 512) return;
    const float* W = (n < 256) ? tutW : tdtW;
    int c = n & 255;
    float s = 0.f;
    for (int k = 0; k < 256; ++k) s += pb[k] * W[k * 256 + c];
    bias1[n] = s;
}

// --------------- attention dot products (paired via blockIdx.y) ------------
__global__ __launch_bounds__(256) void att2_kernel(
    const __half* __restrict__ hWA, const __half* __restrict__ hWB,
    const float* __restrict__ srcA, const float* __restrict__ dstA,
    const float* __restrict__ srcB, const float* __restrict__ dstB,
    float* __restrict__ oSA, float* __restrict__ oDA,
    float* __restrict__ oSB, float* __restrict__ oDB, int n_nodes)
{
    const int g = blockIdx.y;
    const __half* hW = g ? hWB : hWA;
    const float* att_src = g ? srcB : srcA;
    const float* att_dst = g ? dstB : dstA;
    float* a_src = g ? oSB : oSA;
    float* a_dst = g ? oDB : oDA;

    const int wave = threadIdx.x >> 6;
    const int lane = threadIdx.x & 63;
    const int n = blockIdx.x * 4 + wave;
    if (n >= n_nodes) return;

    const __half2* hp = reinterpret_cast<const __half2*>(&hW[(size_t)n * HID + lane * 4]);
    __half2 h01 = hp[0], h23 = hp[1];
    float hx = __low2float(h01), hy = __high2float(h01);
    float hz = __low2float(h23), hw = __high2float(h23);
    float4 s4 = *reinterpret_cast<const float4*>(&att_src[lane * 4]);
    float4 d4 = *reinterpret_cast<const float4*>(&att_dst[lane * 4]);
    float ps = hx * s4.x + hy * s4.y + hz * s4.z + hw * s4.w;
    float pd = hx * d4.x + hy * d4.y + hz * d4.z + hw * d4.w;
    #pragma unroll
    for (int off = 1; off < 8; off <<= 1) {
        ps += __shfl_xor(ps, off);
        pd += __shfl_xor(pd, off);
    }
    if ((lane & 7) == 0) {
        a_src[n * HEADS + (lane >> 3)] = ps;
        a_dst[n * HEADS + (lane >> 3)] = pd;
    }
}

// ---------- GAT two-pass; alpha cached in per-wave LDS ----------
template<int OMODE>
__global__ __launch_bounds__(256) void gat_kernel(
    const __half* __restrict__ hW,
    const float* __restrict__ a_src, const float* __restrict__ a_dst,
    const int* __restrict__ row_ptr, const int* __restrict__ adj,
    const float* __restrict__ bias,
    const unsigned short* __restrict__ prevHi, const unsigned short* __restrict__ prevLo,
    const float* __restrict__ sem,
    unsigned short* __restrict__ outhi, unsigned short* __restrict__ outlo,
    int n_nodes)
{
    __shared__ float elds_all[4][ECAP * 8];   // 6 KB

    const int wave = threadIdx.x >> 6;
    const int lane = threadIdx.x & 63;
    const int n = blockIdx.x * 4 + wave;
    const bool active = (n < n_nodes);
    float* elds = elds_all[wave];

    int beg = 0, end = 0;
    if (active) { beg = row_ptr[n]; end = row_ptr[n + 1]; }
    const int h1 = lane & 7;
    const float adst1 = active ? a_dst[n * HEADS + h1] : 0.f;

    float m = -INFINITY, s = 0.f;
    for (int j = beg + (lane >> 3); j < end; j += 8) {
        float e = a_src[adj[j] * HEADS + h1] + adst1;
        e = (e > 0.f) ? e : NEG_SLOPE * e;
        int jl = j - beg;
        if (jl < ECAP) elds[jl * 8 + h1] = e;
        float mn = fmaxf(m, e);
        float t = (m > -INFINITY) ? s * __expf(m - mn) : 0.f;
        s = t + __expf(e - mn);
        m = mn;
    }
    #pragma unroll
    for (int off = 8; off < 64; off <<= 1) {
        float mo = __shfl_xor(m, off);
        float so = __shfl_xor(s, off);
        float mn = fmaxf(m, mo);
        float t1 = (m  > -INFINITY) ? s  * __expf(m  - mn) : 0.f;
        float t2 = (mo > -INFINITY) ? so * __expf(mo - mn) : 0.f;
        s = t1 + t2;
        m = mn;
    }
    const float inv1 = 1.f / (s + 1e-16f);

    __syncthreads();

    {
        const int cap8 = (active ? ((end - beg < ECAP) ? (end - beg) : ECAP) : 0) * 8;
        for (int idx = lane; idx < cap8; idx += 64)
            elds[idx] = __expf(elds[idx] - m) * inv1;
    }
    __syncthreads();

    const int h2 = lane >> 3;
    const float mh  = __shfl(m, h2);
    const float sh  = __shfl(s, h2);
    const float inv = 1.f / (sh + 1e-16f);
    const float adst2 = active ? a_dst[n * HEADS + h2] : 0.f;
    const int lane4 = lane * 4;

    float4 acc = make_float4(0.f, 0.f, 0.f, 0.f);
    int j = beg;
    for (; j + 4 <= end; j += 4) {
        const int jl = j - beg;
        int s0 = adj[j + 0], s1 = adj[j + 1], s2 = adj[j + 2], s3 = adj[j + 3];
        float al0, al1, al2, al3;
        if (jl + 4 <= ECAP) {
            al0 = elds[(jl + 0) * 8 + h2];
            al1 = elds[(jl + 1) * 8 + h2];
            al2 = elds[(jl + 2) * 8 + h2];
            al3 = elds[(jl + 3) * 8 + h2];
        } else {
            float e0 = a_src[s0 * HEADS + h2] + adst2;
            float e1 = a_src[s1 * HEADS + h2] + adst2;
            float e2 = a_src[s2 * HEADS + h2] + adst2;
            float e3 = a_src[s3 * HEADS + h2] + adst2;
            e0 = (e0 > 0.f) ? e0 : NEG_SLOPE * e0;
            e1 = (e1 > 0.f) ? e1 : NEG_SLOPE * e1;
            e2 = (e2 > 0.f) ? e2 : NEG_SLOPE * e2;
            e3 = (e3 > 0.f) ? e3 : NEG_SLOPE * e3;
            al0 = __expf(e0 - mh) * inv;
            al1 = __expf(e1 - mh) * inv;
            al2 = __expf(e2 - mh) * inv;
            al3 = __expf(e3 - mh) * inv;
        }
        const __half2* p0 = reinterpret_cast<const __half2*>(&hW[(size_t)s0 * HID + lane4]);
        const __half2* p1 = reinterpret_cast<const __half2*>(&hW[(size_t)s1 * HID + lane4]);
        const __half2* p2 = reinterpret_cast<const __half2*>(&hW[(size_t)s2 * HID + lane4]);
        const __half2* p3 = reinterpret_cast<const __half2*>(&hW[(size_t)s3 * HID + lane4]);
        __half2 a01 = p0[0], a23 = p0[1];
        __half2 b01 = p1[0], b23 = p1[1];
        __half2 c01 = p2[0], c23 = p2[1];
        __half2 d01 = p3[0], d23 = p3[1];
        acc.x += al0 * __low2float(a01); acc.y += al0 * __high2float(a01);
        acc.z += al0 * __low2float(a23); acc.w += al0 * __high2float(a23);
        acc.x += al1 * __low2float(b01); acc.y += al1 * __high2float(b01);
        acc.z += al1 * __low2float(b23); acc.w += al1 * __high2float(b23);
        acc.x += al2 * __low2float(c01); acc.y += al2 * __high2float(c01);
        acc.z += al2 * __low2float(c23); acc.w += al2 * __high2float(c23);
        acc.x += al3 * __low2float(d01); acc.y += al3 * __high2float(d01);
        acc.z += al3 * __low2float(d23); acc.w += al3 * __high2float(d23);
    }
    for (; j < end; ++j) {
        const int jl = j - beg;
        int src = adj[j];
        float alpha;
        if (jl < ECAP) {
            alpha = elds[jl * 8 + h2];
        } else {
            float e = a_src[src * HEADS + h2] + adst2;
            e = (e > 0.f) ? e : NEG_SLOPE * e;
            alpha = __expf(e - mh) * inv;
        }
        const __half2* p = reinterpret_cast<const __half2*>(&hW[(size_t)src * HID + lane4]);
        __half2 a01 = p[0], a23 = p[1];
        acc.x += alpha * __low2float(a01); acc.y += alpha * __high2float(a01);
        acc.z += alpha * __low2float(a23); acc.w += alpha * __high2float(a23);
    }

    if (!active) return;

    float4 bv = *reinterpret_cast<const float4*>(&bias[lane4]);
    float4 o;
    o.x = acc.x + bv.x; o.y = acc.y + bv.y; o.z = acc.z + bv.z; o.w = acc.w + bv.w;
    o.x = (o.x > 0.f) ? o.x : expm1f(o.x);
    o.y = (o.y > 0.f) ? o.y : expm1f(o.y);
    o.z = (o.z > 0.f) ? o.z : expm1f(o.z);
    o.w = (o.w > 0.f) ? o.w : expm1f(o.w);

    if (OMODE == 1) {
        const float e0 = __expf(sem[0]);
        const float e1 = __expf(sem[1]);
        const float w0 = e0 / (e0 + e1);
        const float w1 = e1 / (e0 + e1);
        ushort4 ph = *reinterpret_cast<const ushort4*>(&prevHi[(size_t)n * HID + lane4]);
        ushort4 pl = *reinterpret_cast<const ushort4*>(&prevLo[(size_t)n * HID + lane4]);
        o.x = w0 * (bf16_to_f32(ph.x) + bf16_to_f32(pl.x)) + w1 * o.x;
        o.y = w0 * (bf16_to_f32(ph.y) + bf16_to_f32(pl.y)) + w1 * o.y;
        o.z = w0 * (bf16_to_f32(ph.z) + bf16_to_f32(pl.z)) + w1 * o.z;
        o.w = w0 * (bf16_to_f32(ph.w) + bf16_to_f32(pl.w)) + w1 * o.w;
    }

    ushort4 oh, ol;
    split_bf16(o.x, oh.x, ol.x);
    split_bf16(o.y, oh.y, ol.y);
    split_bf16(o.z, oh.z, ol.z);
    split_bf16(o.w, oh.w, ol.w);
    *reinterpret_cast<ushort4*>(&outhi[(size_t)n * HID + lane4]) = oh;
    *reinterpret_cast<ushort4*>(&outlo[(size_t)n * HID + lane4]) = ol;
}

// ------------------- CSR build: bucketed counting sort ---------------------
__global__ __launch_bounds__(256) void bucket_count_kernel(
    const int* __restrict__ tut_dst, const int* __restrict__ tdt_dst,
    int* __restrict__ gcount, int E, int NB)
{
    __shared__ int hist[MAXNB];
    const int g = blockIdx.y;
    const int* dstp = g ? tdt_dst : tut_dst;
    for (int i = threadIdx.x; i < MAXNB; i += 256) hist[i] = 0;
    __syncthreads();
    for (int e = blockIdx.x * 256 + threadIdx.x; e < E; e += gridDim.x * 256)
        atomicAdd(&hist[dstp[e] >> BSH], 1);
    __syncthreads();
    for (int i = threadIdx.x; i < NB; i += 256) {
        int c = hist[i];
        if (c) atomicAdd(&gcount[g * NB + i], c);
    }
}

__global__ __launch_bounds__(512) void bucket_scan_kernel(
    const int* __restrict__ gcount, int* __restrict__ ebase, int* __restrict__ adjbase,
    int* __restrict__ rp0, int* __restrict__ rp1, int N, int E, int NB)
{
    __shared__ int sa[MAXNB], sb[MAXNB];
    const int t = threadIdx.x;
    for (int g = 0; g < 2; ++g) {
        int cnt = (t < NB) ? gcount[g * NB + t] : 0;
        int nodes = 0;
        if (t < NB) { int s = t << BSH; nodes = (N - s < BNODES) ? (N - s) : BNODES; }
        sa[t] = cnt;
        sb[t] = cnt + nodes;
        __syncthreads();
        for (int off = 1; off < MAXNB; off <<= 1) {
            int va = (t >= off) ? sa[t - off] : 0;
            int vb = (t >= off) ? sb[t - off] : 0;
            __syncthreads();
            sa[t] += va; sb[t] += vb;
            __syncthreads();
        }
        if (t < NB) {
            ebase[g * (NB + 1) + t + 1] = sa[t];
            adjbase[g * (NB + 1) + t + 1] = sb[t];
        }
        if (t == 0) { ebase[g * (NB + 1)] = 0; adjbase[g * (NB + 1)] = 0; }
        __syncthreads();
    }
    if (t == 0) { rp0[N] = E + N; rp1[N] = E + N; }
}

__global__ __launch_bounds__(256) void bucket_bin_kernel(
    const int* __restrict__ tut_ei, const int* __restrict__ tdt_ei,
    const int* __restrict__ ebase, int* __restrict__ gcursor,
    int* __restrict__ ebuf, int E, int NB)
{
    __shared__ int lhist[MAXNB];
    __shared__ int lbase[MAXNB];
    __shared__ int loffs[MAXNB];
    __shared__ int spair[CH];
    __shared__ int saddr[CH];
    const int g = blockIdx.y;
    const int* ei = g ? tdt_ei : tut_ei;
    const int e0 = blockIdx.x * CH;
    const int cnt = (E - e0 < CH) ? (E - e0) : CH;

    for (int i = threadIdx.x; i < MAXNB; i += 256) lhist[i] = 0;
    __syncthreads();

    int myb[8], myrank[8], mypk[8];
    int nmine = 0;
    #pragma unroll
    for (int k = 0; k < 8; ++k) {
        int idx = e0 + threadIdx.x + k * 256;
        if (idx < e0 + cnt) {
            int sv = ei[idx];
            int dv = ei[E + idx];
            int b = dv >> BSH;
            int r = atomicAdd(&lhist[b], 1);
            myb[nmine] = b; myrank[nmine] = r;
            mypk[nmine] = (sv << BSH) | (dv & (BNODES - 1));
            ++nmine;
        }
    }
    __syncthreads();
    loffs[threadIdx.x] = lhist[threadIdx.x];
    loffs[threadIdx.x + 256] = lhist[threadIdx.x + 256];
    __syncthreads();
    for (int off = 1; off < MAXNB; off <<= 1) {
        int i0 = threadIdx.x, i1 = threadIdx.x + 256;
        int v0 = (i0 >= off) ? loffs[i0 - off] : 0;
        int v1 = (i1 >= off) ? loffs[i1 - off] : 0;
        __syncthreads();
        loffs[i0] += v0; loffs[i1] += v1;
        __syncthreads();
    }
    for (int i = threadIdx.x; i < NB; i += 256) {
        int c = lhist[i];
        lbase[i] = c ? atomicAdd(&gcursor[g * NB + i], c) : 0;
    }
    __syncthreads();
    const int* eb = ebase + g * (NB + 1);
    for (int k = 0; k < nmine; ++k) {
        int b = myb[k];
        int sorted = loffs[b] - lhist[b] + myrank[k];
        spair[sorted] = mypk[k];
        saddr[sorted] = eb[b] + lbase[b] + myrank[k];
    }
    __syncthreads();
    int* out = ebuf + (size_t)g * E;
    for (int i = threadIdx.x; i < cnt; i += 256)
        out[saddr[i]] = spair[i];
}

__global__ __launch_bounds__(256) void bucket_csr_kernel(
    const int* __restrict__ gcount, const int* __restrict__ ebase,
    const int* __restrict__ adjbase, const int* __restrict__ ebuf,
    int* __restrict__ rp0, int* __restrict__ rp1,
    int* __restrict__ adj0, int* __restrict__ adj1, int N, int E, int NB)
{
    __shared__ int hist[BNODES], scn[BNODES], cursor[BNODES];
    const int g = blockIdx.y;
    const int b = blockIdx.x;
    int* rp  = g ? rp1 : rp0;
    int* adj = g ? adj1 : adj0;
    const int cnt = gcount[g * NB + b];
    const int aB  = adjbase[g * (NB + 1) + b];
    const int node0 = b << BSH;
    const int nb = (N - node0 < BNODES) ? (N - node0) : BNODES;
    const int* ep = ebuf + (size_t)g * E + ebase[g * (NB + 1) + b];
    const int t = threadIdx.x;

    if (t < BNODES) hist[t] = 0;
    __syncthreads();
    for (int e = t; e < cnt; e += 256)
        atomicAdd(&hist[ep[e] & (BNODES - 1)], 1);
    __syncthreads();
    if (t < BNODES) scn[t] = (t < nb) ? hist[t] + 1 : 0;
    __syncthreads();
    for (int off = 1; off < BNODES; off <<= 1) {
        int v = 0;
        if (t < BNODES && t >= off) v = scn[t - off];
        __syncthreads();
        if (t < BNODES) scn[t] += v;
        __syncthreads();
    }
    if (t < nb) {
        int s = scn[t] - hist[t] - 1;
        rp[node0 + t] = aB + s;
        adj[aB + s] = node0 + t;
        cursor[t] = s + 1;
    }
    __syncthreads();
    for (int e = t; e < cnt; e += 256) {
        int p = ep[e];
        int pos = atomicAdd(&cursor[p & (BNODES - 1)], 1);
        adj[aB + pos] = p >> BSH;
    }
}

// ------------------------------- classifier --------------------------------
__global__ __launch_bounds__(256) void cls2_kernel(
    const float* __restrict__ hc, const float* __restrict__ W2,
    const float* __restrict__ b2, float* __restrict__ out, int n_nodes)
{
    const int wave = threadIdx.x >> 6;
    const int lane = threadIdx.x & 63;
    const int n = blockIdx.x * 4 + wave;
    if (n >= n_nodes) return;
    float h0 = hc[(size_t)n * 128 + lane];
    float h1 = hc[(size_t)n * 128 + 64 + lane];
    float p0 = h0 * W2[lane * 2 + 0] + h1 * W2[(64 + lane) * 2 + 0];
    float p1 = h0 * W2[lane * 2 + 1] + h1 * W2[(64 + lane) * 2 + 1];
    #pragma unroll
    for (int off = 1; off < 64; off <<= 1) {
        p0 += __shfl_xor(p0, off);
        p1 += __shfl_xor(p1, off);
    }
    if (lane == 0) {
        out[(size_t)n * 2 + 0] = p0 + b2[0];
        out[(size_t)n * 2 + 1] = p1 + b2[1];
    }
}

// ---------------------------------------------------------------------------
extern "C" void kernel_launch(void* const* d_in, const int* in_sizes, int n_in,
                              void* d_out, int out_size, void* d_ws, size_t ws_size,
                              hipStream_t stream)
{
    const float* x        = (const float*)d_in[0];
    const int*   tut_ei   = (const int*)d_in[1];
    const int*   tdt_ei   = (const int*)d_in[2];
    const float* proj_W   = (const float*)d_in[3];
    const float* proj_b   = (const float*)d_in[4];
    const float* tut_W    = (const float*)d_in[5];
    const float* tut_asrc = (const float*)d_in[6];
    const float* tut_adst = (const float*)d_in[7];
    const float* tut_bias = (const float*)d_in[8];
    const float* tdt_W    = (const float*)d_in[9];
    const float* tdt_asrc = (const float*)d_in[10];
    const float* tdt_adst = (const float*)d_in[11];
    const float* tdt_bias = (const float*)d_in[12];
    const float* sem_att  = (const float*)d_in[13];
    const float* cls_W1   = (const float*)d_in[14];
    const float* cls_b1   = (const float*)d_in[15];
    const float* cls_W2   = (const float*)d_in[16];
    const float* cls_b2   = (const float*)d_in[17];

    const int IN_CH = 128;
    const int N = in_sizes[0] / IN_CH;      // 50000
    const int E = in_sizes[1] / 2;          // 800000
    const int NB = (N + BNODES - 1) >> BSH; // 391
    const size_t NH = (size_t)N * HID;
    const size_t NI = (size_t)N * IN_CH;

    // ------------------------ workspace layout ------------------------
    char* base = (char*)d_ws;
    size_t off = 0;
    auto alloc = [&](size_t bytes) -> void* {
        void* p = base + off;
        off = (off + bytes + 255) & ~(size_t)255;
        return p;
    };
    unsigned short* xhi   = (unsigned short*)alloc(NI * 2);  // +xlo contiguous = t2hi
    unsigned short* xlo   = (unsigned short*)alloc(NI * 2);
    unsigned short* t2lo  = (unsigned short*)alloc(NH * 2);  // also hWb (L1 TDT fp16)
    unsigned short* l1dhi = (unsigned short*)alloc(NH * 2);
    unsigned short* l1dlo = (unsigned short*)alloc(NH * 2);
    unsigned short* l1thi = (unsigned short*)alloc(NH * 2);  // also z hi
    unsigned short* l1tlo = (unsigned short*)alloc(NH * 2);  // also z lo
    __half*         hWa   = (__half*)alloc(NH * 2);          // also ebuf, hc
    __half*         hWc   = (__half*)alloc(NH * 2);          // TDT-L2 hW
    float* as1 = (float*)alloc((size_t)N * HEADS * sizeof(float));
    float* ad1 = (float*)alloc((size_t)N * HEADS * sizeof(float));
    float* as2 = (float*)alloc((size_t)N * HEADS * sizeof(float));
    float* ad2 = (float*)alloc((size_t)N * HEADS * sizeof(float));
    unsigned short* pAhi  = (unsigned short*)alloc(128 * 256 * 2);
    unsigned short* pAlo  = (unsigned short*)alloc(128 * 256 * 2);
    unsigned short* w1hi  = (unsigned short*)alloc(512 * 256 * 2);
    unsigned short* w1lo  = (unsigned short*)alloc(512 * 256 * 2);
    unsigned short* cW1thi = (unsigned short*)alloc(512 * 128 * 2);
    unsigned short* cW1tlo = (unsigned short*)alloc(512 * 128 * 2);
    float* bias1 = (float*)alloc(512 * sizeof(float));
    unsigned short* t2Whi = (unsigned short*)alloc(256 * 256 * 2);
    unsigned short* t2Wlo = (unsigned short*)alloc(256 * 256 * 2);
    unsigned short* d2Whi = (unsigned short*)alloc(256 * 256 * 2);
    unsigned short* d2Wlo = (unsigned short*)alloc(256 * 256 * 2);
    unsigned short* cWthi = (unsigned short*)alloc(128 * 256 * 2);
    unsigned short* cWtlo = (unsigned short*)alloc(128 * 256 * 2);
    int* rp_tut  = (int*)alloc((size_t)(N + 1) * sizeof(int));
    int* adj_tut = (int*)alloc((size_t)(E + N) * sizeof(int));
    int* rp_tdt  = (int*)alloc((size_t)(N + 1) * sizeof(int));
    int* adj_tdt = (int*)alloc((size_t)(E + N) * sizeof(int));
    int* gbuf    = (int*)alloc((size_t)4 * NB * sizeof(int));
    int* gcount  = gbuf;
    int* gcursor = gbuf + 2 * NB;
    int* ebase   = (int*)alloc((size_t)2 * (NB + 1) * sizeof(int));
    int* adjbase = (int*)alloc((size_t)2 * (NB + 1) * sizeof(int));
    (void)ws_size; (void)n_in; (void)out_size;

    int* ebuf = (int*)hWa;                // dead before L1 GEMM writes hWa
    __half* hWb = (__half*)t2lo;          // L1 TDT fp16; t2lo written later
    unsigned short* t2hi = xhi;           // x dead after L1 GEMM
    unsigned short* zhi = l1thi;          // l1t dead after merged L2 GEMM
    unsigned short* zlo = l1tlo;
    float* hc = (float*)hWa;              // hWa dead after TUT-L2 gat

    const int nodeBlocks = (N + 3) / 4;
    const int gy = (N + 127) / 128;
    const int AS = HEADS * (HID / HEADS);

    // --------------- prep + weight fold + CSR build -------------------
    hipMemsetAsync(gbuf, 0, (size_t)4 * NB * sizeof(int), stream);
    prep_kernel<<<1024, 256, 0, stream>>>(proj_W, tut_W, tdt_W, cls_W1,
                                          pAhi, pAlo, w1hi, w1lo, t2Whi, t2Wlo,
                                          d2Whi, d2Wlo, cWthi, cWtlo,
                                          x, xhi, xlo, (int)(NI / 4));
    bias1_kernel<<<2, 256, 0, stream>>>(proj_b, tut_W, tdt_W, bias1);
    mfma_gemm_kernel<3><<<dim3(4, 1), 512, 0, stream>>>(
        pAhi, pAlo, w1hi, w1lo, nullptr, nullptr, nullptr, nullptr,
        nullptr, cW1thi, cW1tlo, nullptr, nullptr, nullptr, nullptr,
        128, 512, 256);
    bucket_count_kernel<<<dim3(128, 2), 256, 0, stream>>>(tut_ei + E, tdt_ei + E, gcount, E, NB);
    bucket_scan_kernel<<<1, 512, 0, stream>>>(gcount, ebase, adjbase, rp_tut, rp_tdt, N, E, NB);
    bucket_bin_kernel<<<dim3((E + CH - 1) / CH, 2), 256, 0, stream>>>(
        tut_ei, tdt_ei, ebase, gcursor, ebuf, E, NB);
    bucket_csr_kernel<<<dim3(NB, 2), 256, 0, stream>>>(
        gcount, ebase, adjbase, ebuf, rp_tut, rp_tdt, adj_tut, adj_tdt, N, E, NB);

    // ------- layer 1 (proj folded in: x @ cW1 + bias1, K=128) ---------
    mfma_gemm_kernel<1><<<dim3(4, gy), 512, 0, stream>>>(
        xhi, xlo, cW1thi, cW1tlo, nullptr, nullptr, nullptr, nullptr,
        bias1, nullptr, nullptr, hWa, hWb, nullptr, nullptr,
        N, 512, 128);
    att2_kernel<<<dim3(nodeBlocks, 2), 256, 0, stream>>>(
        hWa, hWb, tut_asrc, tut_adst, tdt_asrc, tdt_adst,
        as1, ad1, as2, ad2, N);
    gat_kernel<0><<<nodeBlocks, 256, 0, stream>>>(
        hWa, as1, ad1, rp_tut, adj_tut, tut_bias,
        nullptr, nullptr, nullptr, l1thi, l1tlo, N);
    gat_kernel<0><<<nodeBlocks, 256, 0, stream>>>(
        hWb, as2, ad2, rp_tdt, adj_tdt, tdt_bias,
        nullptr, nullptr, nullptr, l1dhi, l1dlo, N);

    // ------------- layer 2 GEMMs merged (blockIdx.z) ------------------
    mfma_gemm_kernel<1><<<dim3(2, gy, 2), 512, 0, stream>>>(
        l1thi, l1tlo, t2Whi, t2Wlo, l1dhi, l1dlo, d2Whi, d2Wlo,
        nullptr, nullptr, nullptr, hWa, nullptr, hWc, nullptr,
        N, HID, HID);
    att2_kernel<<<dim3(nodeBlocks, 2), 256, 0, stream>>>(
        hWa, hWc, tut_asrc + AS, tut_adst + AS, tdt_asrc + AS, tdt_adst + AS,
        as1, ad1, as2, ad2, N);
    gat_kernel<0><<<nodeBlocks, 256, 0, stream>>>(
        hWa, as1, ad1, rp_tut, adj_tut, tut_bias + HID,
        nullptr, nullptr, nullptr, t2hi, t2lo, N);
    gat_kernel<1><<<nodeBlocks, 256, 0, stream>>>(
        hWc, as2, ad2, rp_tdt, adj_tdt, tdt_bias + HID,
        t2hi, t2lo, sem_att, zhi, zlo, N);

    // --------------------------- classifier ---------------------------
    mfma_gemm_kernel<2><<<dim3(1, gy), 512, 0, stream>>>(
        zhi, zlo, cWthi, cWtlo, nullptr, nullptr, nullptr, nullptr,
        cls_b1, nullptr, nullptr, nullptr, nullptr, nullptr, hc,
        N, 128, HID);
    cls2_kernel<<<nodeBlocks, 256, 0, stream>>>(hc, cls_W2, cls_b2, (float*)d_out, N);
}

// Round 18
// 642.808 us; speedup vs baseline: 1.0260x; 1.0260x over previous
//
#include <hip/hip_runtime.h>
#include <hip/hip_fp16.h>
#include <cstddef>
#include <cstdint>

// ---------------------------------------------------------------------------
// SimpleHAN on MI355X — round 17 (revert to measured-best GEMM geometry):
//   - mfma_gemm: BK back to 32 (32KB LDS, 512 threads, 64x32/wave, occ ~52%).
//     BK=64 regressed (m132 pattern: LDS doubling halved residency).
//   - keeps: att2 pairwise merge, proj fold, merged L2 via blockIdx.z,
//     LDS-alpha gat, XCD swizzle, bucketed CSR.
// ---------------------------------------------------------------------------

#define HID        256
#define HEADS      8
#define NEG_SLOPE  0.2f
#define ECAP       48

#define BSH     7
#define BNODES  128
#define MAXNB   512
#define CH      2048

typedef __attribute__((ext_vector_type(8))) short short8v;
typedef __attribute__((ext_vector_type(4))) float float4v;

static __device__ __forceinline__ unsigned short f32_to_bf16(float v) {
    union { float f; unsigned u; } c; c.f = v;
    unsigned r = c.u + 0x7FFFu + ((c.u >> 16) & 1u);
    return (unsigned short)(r >> 16);
}
static __device__ __forceinline__ float bf16_to_f32(unsigned short b) {
    union { unsigned u; float f; } c; c.u = ((unsigned)b) << 16;
    return c.f;
}
static __device__ __forceinline__ void split_bf16(float v, unsigned short& hi, unsigned short& lo) {
    hi = f32_to_bf16(v);
    lo = f32_to_bf16(v - bf16_to_f32(hi));
}
static __device__ __forceinline__ void gload_lds16(const void* g, void* l) {
    __builtin_amdgcn_global_load_lds((const __attribute__((address_space(1))) void*)g,
                                     (__attribute__((address_space(3))) void*)l, 16, 0, 0);
}

// ------------------------- MFMA GEMM (bf16x3 split) ------------------------
// C[M,N] = (Ahi+Alo)[M,K] @ (Bthi+Btlo)[N,K]^T  (+bias)
// 512 threads = 8 waves (2 row-halves x 4 col-quarters); per-wave 64x32; BK=32.
// MODE 1: fp16 out (col<256 -> Cf16a else Cf16b) + bias; blockIdx.z==1
//         switches to operand set 2 and Cf16c.  MODE 2: fp32+bias+relu.
// MODE 3: transposed split bf16 out (weight-fold GEMM).
template<int MODE>
__global__ __launch_bounds__(512) void mfma_gemm_kernel(
    const unsigned short* __restrict__ Ahi, const unsigned short* __restrict__ Alo,
    const unsigned short* __restrict__ Bthi, const unsigned short* __restrict__ Btlo,
    const unsigned short* __restrict__ A2hi, const unsigned short* __restrict__ A2lo,
    const unsigned short* __restrict__ B2thi, const unsigned short* __restrict__ B2tlo,
    const float* __restrict__ bias,
    unsigned short* __restrict__ Chi, unsigned short* __restrict__ Clo,
    __half* __restrict__ Cf16a, __half* __restrict__ Cf16b, __half* __restrict__ Cf16c,
    float* __restrict__ Cf32,
    int M, int N, int K)
{
    __shared__ __align__(16) short lds[4 * 4096];  // 32 KB

    const int tid  = threadIdx.x;
    const int lane = tid & 63;
    const int w    = tid >> 6;        // 0..7
    const int wr   = w >> 2;          // row half (0..1)
    const int wc   = w & 3;           // col quarter (0..3)

    const bool z1 = (blockIdx.z == 1);
    const unsigned short* eAhi  = z1 ? A2hi  : Ahi;
    const unsigned short* eAlo  = z1 ? A2lo  : Alo;
    const unsigned short* eBthi = z1 ? B2thi : Bthi;
    const unsigned short* eBtlo = z1 ? B2tlo : Btlo;
    __half* eCf16a = z1 ? Cf16c : Cf16a;

    // XCD-chunked bijective swizzle (m204)
    const int gx   = gridDim.x;
    const int nwg  = gx * gridDim.y;
    const int flat = blockIdx.y * gx + blockIdx.x;
    const int q    = nwg >> 3, r8 = nwg & 7;
    const int xcd  = flat & 7, idx = flat >> 3;
    const int swz  = (xcd < r8) ? xcd * (q + 1) + idx
                                : r8 * (q + 1) + (xcd - r8) * q + idx;
    const int m0   = (swz / gx) * 128;
    const int n0   = (swz % gx) * 128;

    // staging role: wave pair (w>>1) per array; w&1 selects the 64-row half
    const int sarr  = w >> 1;         // 0..3: Ahi, Alo, Bthi, Btlo
    const int shalf = w & 1;
    const unsigned short* sbase = (sarr == 0) ? eAhi : (sarr == 1) ? eAlo
                                : (sarr == 2) ? eBthi : eBtlo;
    const int rowbase = (sarr < 2) ? m0 : n0;
    const int rowlim  = ((sarr < 2) ? M : N) - 1;

    float4v acc[4][2];
    #pragma unroll
    for (int i = 0; i < 4; ++i)
        #pragma unroll
        for (int j = 0; j < 2; ++j)
            acc[i][j] = (float4v){0.f, 0.f, 0.f, 0.f};

    const int kcl = lane >> 4;
    const int rl  = lane & 15;

    for (int k0 = 0; k0 < K; k0 += 32) {
        {
            int row = rowbase + shalf * 64 + lane;
            row = row > rowlim ? rowlim : row;
            const unsigned short* src = sbase + (size_t)row * K + k0;
            #pragma unroll
            for (int kc = 0; kc < 4; ++kc) {
                short* dst = &lds[sarr * 4096 + kc * 1024 + shalf * 512];
                gload_lds16(src + kc * 8, dst);
            }
        }
        __syncthreads();

        short8v ahi[4], alo[4], bhi[2], blo[2];
        #pragma unroll
        for (int i = 0; i < 4; ++i) {
            int am = wr * 64 + i * 16 + rl;
            ahi[i] = *(const short8v*)&lds[0 * 4096 + kcl * 1024 + am * 8];
            alo[i] = *(const short8v*)&lds[1 * 4096 + kcl * 1024 + am * 8];
        }
        #pragma unroll
        for (int j = 0; j < 2; ++j) {
            int bn = wc * 32 + j * 16 + rl;
            bhi[j] = *(const short8v*)&lds[2 * 4096 + kcl * 1024 + bn * 8];
            blo[j] = *(const short8v*)&lds[3 * 4096 + kcl * 1024 + bn * 8];
        }
        #pragma unroll
        for (int i = 0; i < 4; ++i)
            #pragma unroll
            for (int j = 0; j < 2; ++j) {
                acc[i][j] = __builtin_amdgcn_mfma_f32_16x16x32_bf16(ahi[i], bhi[j], acc[i][j], 0, 0, 0);
                acc[i][j] = __builtin_amdgcn_mfma_f32_16x16x32_bf16(ahi[i], blo[j], acc[i][j], 0, 0, 0);
                acc[i][j] = __builtin_amdgcn_mfma_f32_16x16x32_bf16(alo[i], bhi[j], acc[i][j], 0, 0, 0);
            }
        __syncthreads();
    }

    // ---- epilogue (C/D map: col=lane&15, row=(lane>>4)*4+r) ----
    const int cr = kcl * 4;
    #pragma unroll
    for (int i = 0; i < 4; ++i) {
        #pragma unroll
        for (int r = 0; r < 4; ++r) {
            int row = m0 + wr * 64 + i * 16 + cr + r;
            if (row >= M) continue;
            #pragma unroll
            for (int j = 0; j < 2; ++j) {
                int col = n0 + wc * 32 + j * 16 + rl;
                float v = acc[i][j][r];
                if (bias) v += bias[col];
                if (MODE == 1) {
                    if (col < 256) eCf16a[(size_t)row * 256 + col] = __float2half(v);
                    else           Cf16b[(size_t)row * 256 + (col - 256)] = __float2half(v);
                } else if (MODE == 2) {
                    Cf32[(size_t)row * N + col] = fmaxf(v, 0.f);
                } else {  // MODE 3: transposed split
                    unsigned short h, l;
                    split_bf16(v, h, l);
                    Chi[(size_t)col * M + row] = h;
                    Clo[(size_t)col * M + row] = l;
                }
            }
        }
    }
}

// ----------------------- unified prep (weights + x) ------------------------
__global__ void prep_kernel(
    const float* __restrict__ proj_W, const float* __restrict__ tut_W,
    const float* __restrict__ tdt_W, const float* __restrict__ cls_W1,
    unsigned short* __restrict__ pAhi,  unsigned short* __restrict__ pAlo,
    unsigned short* __restrict__ w1hi,  unsigned short* __restrict__ w1lo,
    unsigned short* __restrict__ t2Whi, unsigned short* __restrict__ t2Wlo,
    unsigned short* __restrict__ d2Whi, unsigned short* __restrict__ d2Wlo,
    unsigned short* __restrict__ cWthi, unsigned short* __restrict__ cWtlo,
    const float* __restrict__ x,
    unsigned short* __restrict__ xhi, unsigned short* __restrict__ xlo, int count4x)
{
    const int tid = blockIdx.x * blockDim.x + threadIdx.x;
    const int stride = gridDim.x * blockDim.x;
    for (int idx = tid; idx < 327680; idx += stride) {
        unsigned short h, l;
        if (idx < 32768) {
            split_bf16(proj_W[idx], h, l);
            pAhi[idx] = h; pAlo[idx] = l;
        } else if (idx < 163840) {
            int r = idx - 32768;
            int ly = r >> 16, rr = r & 65535;
            int k = rr >> 8, n = rr & 255;
            split_bf16(tut_W[r], h, l);
            if (ly == 0) { w1hi[n * 256 + k] = h;  w1lo[n * 256 + k] = l; }
            else         { t2Whi[n * 256 + k] = h; t2Wlo[n * 256 + k] = l; }
        } else if (idx < 294912) {
            int r = idx - 163840;
            int ly = r >> 16, rr = r & 65535;
            int k = rr >> 8, n = rr & 255;
            split_bf16(tdt_W[r], h, l);
            if (ly == 0) { w1hi[(256 + n) * 256 + k] = h; w1lo[(256 + n) * 256 + k] = l; }
            else         { d2Whi[n * 256 + k] = h;        d2Wlo[n * 256 + k] = l; }
        } else {
            int r = idx - 294912;
            int k = r >> 7, n = r & 127;
            split_bf16(cls_W1[r], h, l);
            cWthi[n * 256 + k] = h; cWtlo[n * 256 + k] = l;
        }
    }
    for (int i = tid; i < count4x; i += stride) {
        float4 v = reinterpret_cast<const float4*>(x)[i];
        ushort4 hh, ll;
        split_bf16(v.x, hh.x, ll.x);
        split_bf16(v.y, hh.y, ll.y);
        split_bf16(v.z, hh.z, ll.z);
        split_bf16(v.w, hh.w, ll.w);
        reinterpret_cast<ushort4*>(xhi)[i] = hh;
        reinterpret_cast<ushort4*>(xlo)[i] = ll;
    }
}

// bias1[n] = sum_k proj_b[k] * W1cat[k, n]   (fp32 exact)
__global__ void bias1_kernel(const float* __restrict__ pb,
                             const float* __restrict__ tutW,
                             const float* __restrict__ tdtW,
                             float* __restrict__ bias1)
{
    int n = blockIdx.x * blockDim.x + threadIdx.x;
    if (n >= 512) return;
    const float* W = (n < 256) ? tutW : tdtW;
    int c = n & 255;
    float s = 0.f;
    for (int k = 0; k < 256; ++k) s += pb[k] * W[k * 256 + c];
    bias1[n] = s;
}

// --------------- attention dot products (paired via blockIdx.y) ------------
__global__ __launch_bounds__(256) void att2_kernel(
    const __half* __restrict__ hWA, const __half* __restrict__ hWB,
    const float* __restrict__ srcA, const float* __restrict__ dstA,
    const float* __restrict__ srcB, const float* __restrict__ dstB,
    float* __restrict__ oSA, float* __restrict__ oDA,
    float* __restrict__ oSB, float* __restrict__ oDB, int n_nodes)
{
    const int g = blockIdx.y;
    const __half* hW = g ? hWB : hWA;
    const float* att_src = g ? srcB : srcA;
    const float* att_dst = g ? dstB : dstA;
    float* a_src = g ? oSB : oSA;
    float* a_dst = g ? oDB : oDA;

    const int wave = threadIdx.x >> 6;
    const int lane = threadIdx.x & 63;
    const int n = blockIdx.x * 4 + wave;
    if (n >= n_nodes) return;

    const __half2* hp = reinterpret_cast<const __half2*>(&hW[(size_t)n * HID + lane * 4]);
    __half2 h01 = hp[0], h23 = hp[1];
    float hx = __low2float(h01), hy = __high2float(h01);
    float hz = __low2float(h23), hw = __high2float(h23);
    float4 s4 = *reinterpret_cast<const float4*>(&att_src[lane * 4]);
    float4 d4 = *reinterpret_cast<const float4*>(&att_dst[lane * 4]);
    float ps = hx * s4.x + hy * s4.y + hz * s4.z + hw * s4.w;
    float pd = hx * d4.x + hy * d4.y + hz * d4.z + hw * d4.w;
    #pragma unroll
    for (int off = 1; off < 8; off <<= 1) {
        ps += __shfl_xor(ps, off);
        pd += __shfl_xor(pd, off);
    }
    if ((lane & 7) == 0) {
        a_src[n * HEADS + (lane >> 3)] = ps;
        a_dst[n * HEADS + (lane >> 3)] = pd;
    }
}

// ---------- GAT two-pass; alpha cached in per-wave LDS ----------
template<int OMODE>
__global__ __launch_bounds__(256) void gat_kernel(
    const __half* __restrict__ hW,
    const float* __restrict__ a_src, const float* __restrict__ a_dst,
    const int* __restrict__ row_ptr, const int* __restrict__ adj,
    const float* __restrict__ bias,
    const unsigned short* __restrict__ prevHi, const unsigned short* __restrict__ prevLo,
    const float* __restrict__ sem,
    unsigned short* __restrict__ outhi, unsigned short* __restrict__ outlo,
    int n_nodes)
{
    __shared__ float elds_all[4][ECAP * 8];   // 6 KB

    const int wave = threadIdx.x >> 6;
    const int lane = threadIdx.x & 63;
    const int n = blockIdx.x * 4 + wave;
    const bool active = (n < n_nodes);
    float* elds = elds_all[wave];

    int beg = 0, end = 0;
    if (active) { beg = row_ptr[n]; end = row_ptr[n + 1]; }
    const int h1 = lane & 7;
    const float adst1 = active ? a_dst[n * HEADS + h1] : 0.f;

    float m = -INFINITY, s = 0.f;
    for (int j = beg + (lane >> 3); j < end; j += 8) {
        float e = a_src[adj[j] * HEADS + h1] + adst1;
        e = (e > 0.f) ? e : NEG_SLOPE * e;
        int jl = j - beg;
        if (jl < ECAP) elds[jl * 8 + h1] = e;
        float mn = fmaxf(m, e);
        float t = (m > -INFINITY) ? s * __expf(m - mn) : 0.f;
        s = t + __expf(e - mn);
        m = mn;
    }
    #pragma unroll
    for (int off = 8; off < 64; off <<= 1) {
        float mo = __shfl_xor(m, off);
        float so = __shfl_xor(s, off);
        float mn = fmaxf(m, mo);
        float t1 = (m  > -INFINITY) ? s  * __expf(m  - mn) : 0.f;
        float t2 = (mo > -INFINITY) ? so * __expf(mo - mn) : 0.f;
        s = t1 + t2;
        m = mn;
    }
    const float inv1 = 1.f / (s + 1e-16f);

    __syncthreads();

    {
        const int cap8 = (active ? ((end - beg < ECAP) ? (end - beg) : ECAP) : 0) * 8;
        for (int idx = lane; idx < cap8; idx += 64)
            elds[idx] = __expf(elds[idx] - m) * inv1;
    }
    __syncthreads();

    const int h2 = lane >> 3;
    const float mh  = __shfl(m, h2);
    const float sh  = __shfl(s, h2);
    const float inv = 1.f / (sh + 1e-16f);
    const float adst2 = active ? a_dst[n * HEADS + h2] : 0.f;
    const int lane4 = lane * 4;

    float4 acc = make_float4(0.f, 0.f, 0.f, 0.f);
    int j = beg;
    for (; j + 4 <= end; j += 4) {
        const int jl = j - beg;
        int s0 = adj[j + 0], s1 = adj[j + 1], s2 = adj[j + 2], s3 = adj[j + 3];
        float al0, al1, al2, al3;
        if (jl + 4 <= ECAP) {
            al0 = elds[(jl + 0) * 8 + h2];
            al1 = elds[(jl + 1) * 8 + h2];
            al2 = elds[(jl + 2) * 8 + h2];
            al3 = elds[(jl + 3) * 8 + h2];
        } else {
            float e0 = a_src[s0 * HEADS + h2] + adst2;
            float e1 = a_src[s1 * HEADS + h2] + adst2;
            float e2 = a_src[s2 * HEADS + h2] + adst2;
            float e3 = a_src[s3 * HEADS + h2] + adst2;
            e0 = (e0 > 0.f) ? e0 : NEG_SLOPE * e0;
            e1 = (e1 > 0.f) ? e1 : NEG_SLOPE * e1;
            e2 = (e2 > 0.f) ? e2 : NEG_SLOPE * e2;
            e3 = (e3 > 0.f) ? e3 : NEG_SLOPE * e3;
            al0 = __expf(e0 - mh) * inv;
            al1 = __expf(e1 - mh) * inv;
            al2 = __expf(e2 - mh) * inv;
            al3 = __expf(e3 - mh) * inv;
        }
        const __half2* p0 = reinterpret_cast<const __half2*>(&hW[(size_t)s0 * HID + lane4]);
        const __half2* p1 = reinterpret_cast<const __half2*>(&hW[(size_t)s1 * HID + lane4]);
        const __half2* p2 = reinterpret_cast<const __half2*>(&hW[(size_t)s2 * HID + lane4]);
        const __half2* p3 = reinterpret_cast<const __half2*>(&hW[(size_t)s3 * HID + lane4]);
        __half2 a01 = p0[0], a23 = p0[1];
        __half2 b01 = p1[0], b23 = p1[1];
        __half2 c01 = p2[0], c23 = p2[1];
        __half2 d01 = p3[0], d23 = p3[1];
        acc.x += al0 * __low2float(a01); acc.y += al0 * __high2float(a01);
        acc.z += al0 * __low2float(a23); acc.w += al0 * __high2float(a23);
        acc.x += al1 * __low2float(b01); acc.y += al1 * __high2float(b01);
        acc.z += al1 * __low2float(b23); acc.w += al1 * __high2float(b23);
        acc.x += al2 * __low2float(c01); acc.y += al2 * __high2float(c01);
        acc.z += al2 * __low2float(c23); acc.w += al2 * __high2float(c23);
        acc.x += al3 * __low2float(d01); acc.y += al3 * __high2float(d01);
        acc.z += al3 * __low2float(d23); acc.w += al3 * __high2float(d23);
    }
    for (; j < end; ++j) {
        const int jl = j - beg;
        int src = adj[j];
        float alpha;
        if (jl < ECAP) {
            alpha = elds[jl * 8 + h2];
        } else {
            float e = a_src[src * HEADS + h2] + adst2;
            e = (e > 0.f) ? e : NEG_SLOPE * e;
            alpha = __expf(e - mh) * inv;
        }
        const __half2* p = reinterpret_cast<const __half2*>(&hW[(size_t)src * HID + lane4]);
        __half2 a01 = p[0], a23 = p[1];
        acc.x += alpha * __low2float(a01); acc.y += alpha * __high2float(a01);
        acc.z += alpha * __low2float(a23); acc.w += alpha * __high2float(a23);
    }

    if (!active) return;

    float4 bv = *reinterpret_cast<const float4*>(&bias[lane4]);
    float4 o;
    o.x = acc.x + bv.x; o.y = acc.y + bv.y; o.z = acc.z + bv.z; o.w = acc.w + bv.w;
    o.x = (o.x > 0.f) ? o.x : expm1f(o.x);
    o.y = (o.y > 0.f) ? o.y : expm1f(o.y);
    o.z = (o.z > 0.f) ? o.z : expm1f(o.z);
    o.w = (o.w > 0.f) ? o.w : expm1f(o.w);

    if (OMODE == 1) {
        const float e0 = __expf(sem[0]);
        const float e1 = __expf(sem[1]);
        const float w0 = e0 / (e0 + e1);
        const float w1 = e1 / (e0 + e1);
        ushort4 ph = *reinterpret_cast<const ushort4*>(&prevHi[(size_t)n * HID + lane4]);
        ushort4 pl = *reinterpret_cast<const ushort4*>(&prevLo[(size_t)n * HID + lane4]);
        o.x = w0 * (bf16_to_f32(ph.x) + bf16_to_f32(pl.x)) + w1 * o.x;
        o.y = w0 * (bf16_to_f32(ph.y) + bf16_to_f32(pl.y)) + w1 * o.y;
        o.z = w0 * (bf16_to_f32(ph.z) + bf16_to_f32(pl.z)) + w1 * o.z;
        o.w = w0 * (bf16_to_f32(ph.w) + bf16_to_f32(pl.w)) + w1 * o.w;
    }

    ushort4 oh, ol;
    split_bf16(o.x, oh.x, ol.x);
    split_bf16(o.y, oh.y, ol.y);
    split_bf16(o.z, oh.z, ol.z);
    split_bf16(o.w, oh.w, ol.w);
    *reinterpret_cast<ushort4*>(&outhi[(size_t)n * HID + lane4]) = oh;
    *reinterpret_cast<ushort4*>(&outlo[(size_t)n * HID + lane4]) = ol;
}

// ------------------- CSR build: bucketed counting sort ---------------------
__global__ __launch_bounds__(256) void bucket_count_kernel(
    const int* __restrict__ tut_dst, const int* __restrict__ tdt_dst,
    int* __restrict__ gcount, int E, int NB)
{
    __shared__ int hist[MAXNB];
    const int g = blockIdx.y;
    const int* dstp = g ? tdt_dst : tut_dst;
    for (int i = threadIdx.x; i < MAXNB; i += 256) hist[i] = 0;
    __syncthreads();
    for (int e = blockIdx.x * 256 + threadIdx.x; e < E; e += gridDim.x * 256)
        atomicAdd(&hist[dstp[e] >> BSH], 1);
    __syncthreads();
    for (int i = threadIdx.x; i < NB; i += 256) {
        int c = hist[i];
        if (c) atomicAdd(&gcount[g * NB + i], c);
    }
}

__global__ __launch_bounds__(512) void bucket_scan_kernel(
    const int* __restrict__ gcount, int* __restrict__ ebase, int* __restrict__ adjbase,
    int* __restrict__ rp0, int* __restrict__ rp1, int N, int E, int NB)
{
    __shared__ int sa[MAXNB], sb[MAXNB];
    const int t = threadIdx.x;
    for (int g = 0; g < 2; ++g) {
        int cnt = (t < NB) ? gcount[g * NB + t] : 0;
        int nodes = 0;
        if (t < NB) { int s = t << BSH; nodes = (N - s < BNODES) ? (N - s) : BNODES; }
        sa[t] = cnt;
        sb[t] = cnt + nodes;
        __syncthreads();
        for (int off = 1; off < MAXNB; off <<= 1) {
            int va = (t >= off) ? sa[t - off] : 0;
            int vb = (t >= off) ? sb[t - off] : 0;
            __syncthreads();
            sa[t] += va; sb[t] += vb;
            __syncthreads();
        }
        if (t < NB) {
            ebase[g * (NB + 1) + t + 1] = sa[t];
            adjbase[g * (NB + 1) + t + 1] = sb[t];
        }
        if (t == 0) { ebase[g * (NB + 1)] = 0; adjbase[g * (NB + 1)] = 0; }
        __syncthreads();
    }
    if (t == 0) { rp0[N] = E + N; rp1[N] = E + N; }
}

__global__ __launch_bounds__(256) void bucket_bin_kernel(
    const int* __restrict__ tut_ei, const int* __restrict__ tdt_ei,
    const int* __restrict__ ebase, int* __restrict__ gcursor,
    int* __restrict__ ebuf, int E, int NB)
{
    __shared__ int lhist[MAXNB];
    __shared__ int lbase[MAXNB];
    __shared__ int loffs[MAXNB];
    __shared__ int spair[CH];
    __shared__ int saddr[CH];
    const int g = blockIdx.y;
    const int* ei = g ? tdt_ei : tut_ei;
    const int e0 = blockIdx.x * CH;
    const int cnt = (E - e0 < CH) ? (E - e0) : CH;

    for (int i = threadIdx.x; i < MAXNB; i += 256) lhist[i] = 0;
    __syncthreads();

    int myb[8], myrank[8], mypk[8];
    int nmine = 0;
    #pragma unroll
    for (int k = 0; k < 8; ++k) {
        int idx = e0 + threadIdx.x + k * 256;
        if (idx < e0 + cnt) {
            int sv = ei[idx];
            int dv = ei[E + idx];
            int b = dv >> BSH;
            int r = atomicAdd(&lhist[b], 1);
            myb[nmine] = b; myrank[nmine] = r;
            mypk[nmine] = (sv << BSH) | (dv & (BNODES - 1));
            ++nmine;
        }
    }
    __syncthreads();
    loffs[threadIdx.x] = lhist[threadIdx.x];
    loffs[threadIdx.x + 256] = lhist[threadIdx.x + 256];
    __syncthreads();
    for (int off = 1; off < MAXNB; off <<= 1) {
        int i0 = threadIdx.x, i1 = threadIdx.x + 256;
        int v0 = (i0 >= off) ? loffs[i0 - off] : 0;
        int v1 = (i1 >= off) ? loffs[i1 - off] : 0;
        __syncthreads();
        loffs[i0] += v0; loffs[i1] += v1;
        __syncthreads();
    }
    for (int i = threadIdx.x; i < NB; i += 256) {
        int c = lhist[i];
        lbase[i] = c ? atomicAdd(&gcursor[g * NB + i], c) : 0;
    }
    __syncthreads();
    const int* eb = ebase + g * (NB + 1);
    for (int k = 0; k < nmine; ++k) {
        int b = myb[k];
        int sorted = loffs[b] - lhist[b] + myrank[k];
        spair[sorted] = mypk[k];
        saddr[sorted] = eb[b] + lbase[b] + myrank[k];
    }
    __syncthreads();
    int* out = ebuf + (size_t)g * E;
    for (int i = threadIdx.x; i < cnt; i += 256)
        out[saddr[i]] = spair[i];
}

__global__ __launch_bounds__(256) void bucket_csr_kernel(
    const int* __restrict__ gcount, const int* __restrict__ ebase,
    const int* __restrict__ adjbase, const int* __restrict__ ebuf,
    int* __restrict__ rp0, int* __restrict__ rp1,
    int* __restrict__ adj0, int* __restrict__ adj1, int N, int E, int NB)
{
    __shared__ int hist[BNODES], scn[BNODES], cursor[BNODES];
    const int g = blockIdx.y;
    const int b = blockIdx.x;
    int* rp  = g ? rp1 : rp0;
    int* adj = g ? adj1 : adj0;
    const int cnt = gcount[g * NB + b];
    const int aB  = adjbase[g * (NB + 1) + b];
    const int node0 = b << BSH;
    const int nb = (N - node0 < BNODES) ? (N - node0) : BNODES;
    const int* ep = ebuf + (size_t)g * E + ebase[g * (NB + 1) + b];
    const int t = threadIdx.x;

    if (t < BNODES) hist[t] = 0;
    __syncthreads();
    for (int e = t; e < cnt; e += 256)
        atomicAdd(&hist[ep[e] & (BNODES - 1)], 1);
    __syncthreads();
    if (t < BNODES) scn[t] = (t < nb) ? hist[t] + 1 : 0;
    __syncthreads();
    for (int off = 1; off < BNODES; off <<= 1) {
        int v = 0;
        if (t < BNODES && t >= off) v = scn[t - off];
        __syncthreads();
        if (t < BNODES) scn[t] += v;
        __syncthreads();
    }
    if (t < nb) {
        int s = scn[t] - hist[t] - 1;
        rp[node0 + t] = aB + s;
        adj[aB + s] = node0 + t;
        cursor[t] = s + 1;
    }
    __syncthreads();
    for (int e = t; e < cnt; e += 256) {
        int p = ep[e];
        int pos = atomicAdd(&cursor[p & (BNODES - 1)], 1);
        adj[aB + pos] = p >> BSH;
    }
}

// ------------------------------- classifier --------------------------------
__global__ __launch_bounds__(256) void cls2_kernel(
    const float* __restrict__ hc, const float* __restrict__ W2,
    const float* __restrict__ b2, float* __restrict__ out, int n_nodes)
{
    const int wave = threadIdx.x >> 6;
    const int lane = threadIdx.x & 63;
    const int n = blockIdx.x * 4 + wave;
    if (n >= n_nodes) return;
    float h0 = hc[(size_t)n * 128 + lane];
    float h1 = hc[(size_t)n * 128 + 64 + lane];
    float p0 = h0 * W2[lane * 2 + 0] + h1 * W2[(64 + lane) * 2 + 0];
    float p1 = h0 * W2[lane * 2 + 1] + h1 * W2[(64 + lane) * 2 + 1];
    #pragma unroll
    for (int off = 1; off < 64; off <<= 1) {
        p0 += __shfl_xor(p0, off);
        p1 += __shfl_xor(p1, off);
    }
    if (lane == 0) {
        out[(size_t)n * 2 + 0] = p0 + b2[0];
        out[(size_t)n * 2 + 1] = p1 + b2[1];
    }
}

// ---------------------------------------------------------------------------
extern "C" void kernel_launch(void* const* d_in, const int* in_sizes, int n_in,
                              void* d_out, int out_size, void* d_ws, size_t ws_size,
                              hipStream_t stream)
{
    const float* x        = (const float*)d_in[0];
    const int*   tut_ei   = (const int*)d_in[1];
    const int*   tdt_ei   = (const int*)d_in[2];
    const float* proj_W   = (const float*)d_in[3];
    const float* proj_b   = (const float*)d_in[4];
    const float* tut_W    = (const float*)d_in[5];
    const float* tut_asrc = (const float*)d_in[6];
    const float* tut_adst = (const float*)d_in[7];
    const float* tut_bias = (const float*)d_in[8];
    const float* tdt_W    = (const float*)d_in[9];
    const float* tdt_asrc = (const float*)d_in[10];
    const float* tdt_adst = (const float*)d_in[11];
    const float* tdt_bias = (const float*)d_in[12];
    const float* sem_att  = (const float*)d_in[13];
    const float* cls_W1   = (const float*)d_in[14];
    const float* cls_b1   = (const float*)d_in[15];
    const float* cls_W2   = (const float*)d_in[16];
    const float* cls_b2   = (const float*)d_in[17];

    const int IN_CH = 128;
    const int N = in_sizes[0] / IN_CH;      // 50000
    const int E = in_sizes[1] / 2;          // 800000
    const int NB = (N + BNODES - 1) >> BSH; // 391
    const size_t NH = (size_t)N * HID;
    const size_t NI = (size_t)N * IN_CH;

    // ------------------------ workspace layout ------------------------
    char* base = (char*)d_ws;
    size_t off = 0;
    auto alloc = [&](size_t bytes) -> void* {
        void* p = base + off;
        off = (off + bytes + 255) & ~(size_t)255;
        return p;
    };
    unsigned short* xhi   = (unsigned short*)alloc(NI * 2);  // +xlo contiguous = t2hi
    unsigned short* xlo   = (unsigned short*)alloc(NI * 2);
    unsigned short* t2lo  = (unsigned short*)alloc(NH * 2);  // also hWb (L1 TDT fp16)
    unsigned short* l1dhi = (unsigned short*)alloc(NH * 2);
    unsigned short* l1dlo = (unsigned short*)alloc(NH * 2);
    unsigned short* l1thi = (unsigned short*)alloc(NH * 2);  // also z hi
    unsigned short* l1tlo = (unsigned short*)alloc(NH * 2);  // also z lo
    __half*         hWa   = (__half*)alloc(NH * 2);          // also ebuf, hc
    __half*         hWc   = (__half*)alloc(NH * 2);          // TDT-L2 hW
    float* as1 = (float*)alloc((size_t)N * HEADS * sizeof(float));
    float* ad1 = (float*)alloc((size_t)N * HEADS * sizeof(float));
    float* as2 = (float*)alloc((size_t)N * HEADS * sizeof(float));
    float* ad2 = (float*)alloc((size_t)N * HEADS * sizeof(float));
    unsigned short* pAhi  = (unsigned short*)alloc(128 * 256 * 2);
    unsigned short* pAlo  = (unsigned short*)alloc(128 * 256 * 2);
    unsigned short* w1hi  = (unsigned short*)alloc(512 * 256 * 2);
    unsigned short* w1lo  = (unsigned short*)alloc(512 * 256 * 2);
    unsigned short* cW1thi = (unsigned short*)alloc(512 * 128 * 2);
    unsigned short* cW1tlo = (unsigned short*)alloc(512 * 128 * 2);
    float* bias1 = (float*)alloc(512 * sizeof(float));
    unsigned short* t2Whi = (unsigned short*)alloc(256 * 256 * 2);
    unsigned short* t2Wlo = (unsigned short*)alloc(256 * 256 * 2);
    unsigned short* d2Whi = (unsigned short*)alloc(256 * 256 * 2);
    unsigned short* d2Wlo = (unsigned short*)alloc(256 * 256 * 2);
    unsigned short* cWthi = (unsigned short*)alloc(128 * 256 * 2);
    unsigned short* cWtlo = (unsigned short*)alloc(128 * 256 * 2);
    int* rp_tut  = (int*)alloc((size_t)(N + 1) * sizeof(int));
    int* adj_tut = (int*)alloc((size_t)(E + N) * sizeof(int));
    int* rp_tdt  = (int*)alloc((size_t)(N + 1) * sizeof(int));
    int* adj_tdt = (int*)alloc((size_t)(E + N) * sizeof(int));
    int* gbuf    = (int*)alloc((size_t)4 * NB * sizeof(int));
    int* gcount  = gbuf;
    int* gcursor = gbuf + 2 * NB;
    int* ebase   = (int*)alloc((size_t)2 * (NB + 1) * sizeof(int));
    int* adjbase = (int*)alloc((size_t)2 * (NB + 1) * sizeof(int));
    (void)ws_size; (void)n_in; (void)out_size;

    int* ebuf = (int*)hWa;                // dead before L1 GEMM writes hWa
    __half* hWb = (__half*)t2lo;          // L1 TDT fp16; t2lo written later
    unsigned short* t2hi = xhi;           // x dead after L1 GEMM
    unsigned short* zhi = l1thi;          // l1t dead after merged L2 GEMM
    unsigned short* zlo = l1tlo;
    float* hc = (float*)hWa;              // hWa dead after TUT-L2 gat

    const int nodeBlocks = (N + 3) / 4;
    const int gy = (N + 127) / 128;
    const int AS = HEADS * (HID / HEADS);

    // --------------- prep + weight fold + CSR build -------------------
    hipMemsetAsync(gbuf, 0, (size_t)4 * NB * sizeof(int), stream);
    prep_kernel<<<1024, 256, 0, stream>>>(proj_W, tut_W, tdt_W, cls_W1,
                                          pAhi, pAlo, w1hi, w1lo, t2Whi, t2Wlo,
                                          d2Whi, d2Wlo, cWthi, cWtlo,
                                          x, xhi, xlo, (int)(NI / 4));
    bias1_kernel<<<2, 256, 0, stream>>>(proj_b, tut_W, tdt_W, bias1);
    mfma_gemm_kernel<3><<<dim3(4, 1), 512, 0, stream>>>(
        pAhi, pAlo, w1hi, w1lo, nullptr, nullptr, nullptr, nullptr,
        nullptr, cW1thi, cW1tlo, nullptr, nullptr, nullptr, nullptr,
        128, 512, 256);
    bucket_count_kernel<<<dim3(128, 2), 256, 0, stream>>>(tut_ei + E, tdt_ei + E, gcount, E, NB);
    bucket_scan_kernel<<<1, 512, 0, stream>>>(gcount, ebase, adjbase, rp_tut, rp_tdt, N, E, NB);
    bucket_bin_kernel<<<dim3((E + CH - 1) / CH, 2), 256, 0, stream>>>(
        tut_ei, tdt_ei, ebase, gcursor, ebuf, E, NB);
    bucket_csr_kernel<<<dim3(NB, 2), 256, 0, stream>>>(
        gcount, ebase, adjbase, ebuf, rp_tut, rp_tdt, adj_tut, adj_tdt, N, E, NB);

    // ------- layer 1 (proj folded in: x @ cW1 + bias1, K=128) ---------
    mfma_gemm_kernel<1><<<dim3(4, gy), 512, 0, stream>>>(
        xhi, xlo, cW1thi, cW1tlo, nullptr, nullptr, nullptr, nullptr,
        bias1, nullptr, nullptr, hWa, hWb, nullptr, nullptr,
        N, 512, 128);
    att2_kernel<<<dim3(nodeBlocks, 2), 256, 0, stream>>>(
        hWa, hWb, tut_asrc, tut_adst, tdt_asrc, tdt_adst,
        as1, ad1, as2, ad2, N);
    gat_kernel<0><<<nodeBlocks, 256, 0, stream>>>(
        hWa, as1, ad1, rp_tut, adj_tut, tut_bias,
        nullptr, nullptr, nullptr, l1thi, l1tlo, N);
    gat_kernel<0><<<nodeBlocks, 256, 0, stream>>>(
        hWb, as2, ad2, rp_tdt, adj_tdt, tdt_bias,
        nullptr, nullptr, nullptr, l1dhi, l1dlo, N);

    // ------------- layer 2 GEMMs merged (blockIdx.z) ------------------
    mfma_gemm_kernel<1><<<dim3(2, gy, 2), 512, 0, stream>>>(
        l1thi, l1tlo, t2Whi, t2Wlo, l1dhi, l1dlo, d2Whi, d2Wlo,
        nullptr, nullptr, nullptr, hWa, nullptr, hWc, nullptr,
        N, HID, HID);
    att2_kernel<<<dim3(nodeBlocks, 2), 256, 0, stream>>>(
        hWa, hWc, tut_asrc + AS, tut_adst + AS, tdt_asrc + AS, tdt_adst + AS,
        as1, ad1, as2, ad2, N);
    gat_kernel<0><<<nodeBlocks, 256, 0, stream>>>(
        hWa, as1, ad1, rp_tut, adj_tut, tut_bias + HID,
        nullptr, nullptr, nullptr, t2hi, t2lo, N);
    gat_kernel<1><<<nodeBlocks, 256, 0, stream>>>(
        hWc, as2, ad2, rp_tdt, adj_tdt, tdt_bias + HID,
        t2hi, t2lo, sem_att, zhi, zlo, N);

    // --------------------------- classifier ---------------------------
    mfma_gemm_kernel<2><<<dim3(1, gy), 512, 0, stream>>>(
        zhi, zlo, cWthi, cWtlo, nullptr, nullptr, nullptr, nullptr,
        cls_b1, nullptr, nullptr, nullptr, nullptr, nullptr, hc,
        N, 128, HID);
    cls2_kernel<<<nodeBlocks, 256, 0, stream>>>(hc, cls_W2, cls_b2, (float*)d_out, N);
}